// Round 2
// 317.577 us; speedup vs baseline: 1.5186x; 1.5186x over previous
//
#include <hip/hip_runtime.h>

#define TT 2048
#define BB 8
#define DD 1024
#define NN 64
#define C64 64            // timesteps per chunk (= wavefront size)
#define NC2 (TT / C64)    // 32 chunks

typedef __attribute__((ext_vector_type(8))) short bfrag;    // 8 bf16 (4 VGPRs)
typedef __attribute__((ext_vector_type(4))) float f32x4;    // MFMA C/D
typedef __attribute__((ext_vector_type(8))) unsigned short ushort8;

__device__ __forceinline__ float rcp_(float x) { return __builtin_amdgcn_rcpf(x); }
__device__ __forceinline__ float exp2_(float x) {
#if __has_builtin(__builtin_amdgcn_exp2f)
    return __builtin_amdgcn_exp2f(x);
#else
    return exp2f(x);
#endif
}
// fast sigmoid for proj epilogue
__device__ __forceinline__ float sigmoidf_(float x) {
    return rcp_(1.0f + __expf(-x));
}
__device__ __forceinline__ float bcastlane(float x, int l) {
    return __int_as_float(__builtin_amdgcn_readlane(__float_as_int(x), l));
}

// f32 -> bf16 round-to-nearest-even
__device__ __forceinline__ unsigned short cvt_bf16(float f) {
    unsigned int u = __float_as_uint(f);
    return (unsigned short)((u + 0x7FFF + ((u >> 16) & 1)) >> 16);
}

// async global->LDS, 16 B/lane (LDS dest is wave-uniform base + lane*16)
__device__ __forceinline__ void gll16(const float* g, float* l) {
    __builtin_amdgcn_global_load_lds(
        (const __attribute__((address_space(1))) void*)g,
        (__attribute__((address_space(3))) void*)l, 16, 0, 0);
}

// ---------------------------------------------------------------------------
// Phase 1: projections via bf16 MFMA (unchanged, known good).
// ---------------------------------------------------------------------------
__global__ __launch_bounds__(256) void proj_gemm_kernel(
    const float* __restrict__ x,
    const float* __restrict__ W0, const float* __restrict__ W1,
    const float* __restrict__ W2, const float* __restrict__ W3,
    const float* __restrict__ b_alpha,
    float* __restrict__ O0, float* __restrict__ O1,
    float* __restrict__ O2, float* __restrict__ O3)
{
    const int mat = blockIdx.x;
    const float* __restrict__ W = (mat == 0) ? W0 : (mat == 1) ? W1 : (mat == 2) ? W2 : W3;
    float* __restrict__ C       = (mat == 0) ? O0 : (mat == 1) ? O1 : (mat == 2) ? O2 : O3;

    const int m0   = blockIdx.y * 128;
    const int tid  = threadIdx.x;
    const int lane = tid & 63;
    const int wave = tid >> 6;
    const int ln   = lane & 15;
    const int q8   = (lane >> 4) * 8;

    __shared__ unsigned short As[128][40];
    __shared__ unsigned short Bs[64][40];

    f32x4 acc[2][4] = {};

    const int arow = tid >> 1;
    const int aseg = (tid & 1) * 16;

    float4 pa[4], pb[4];
    {
        const float* ap = &x[(size_t)(m0 + arow) * DD + aseg];
        #pragma unroll
        for (int j = 0; j < 4; j++) pa[j] = *(const float4*)(ap + 4 * j);
        if (tid < 128) {
            const float* bp = &W[(size_t)arow * DD + aseg];
            #pragma unroll
            for (int j = 0; j < 4; j++) pb[j] = *(const float4*)(bp + 4 * j);
        }
    }

    for (int k0 = 0; k0 < DD; k0 += 32) {
        __syncthreads();
        {
            unsigned short t16[16];
            const float* pf = (const float*)pa;
            #pragma unroll
            for (int j = 0; j < 16; j++) t16[j] = cvt_bf16(pf[j]);
            *(ushort8*)&As[arow][aseg]     = *(ushort8*)&t16[0];
            *(ushort8*)&As[arow][aseg + 8] = *(ushort8*)&t16[8];
            if (tid < 128) {
                const float* qf = (const float*)pb;
                #pragma unroll
                for (int j = 0; j < 16; j++) t16[j] = cvt_bf16(qf[j]);
                *(ushort8*)&Bs[arow][aseg]     = *(ushort8*)&t16[0];
                *(ushort8*)&Bs[arow][aseg + 8] = *(ushort8*)&t16[8];
            }
        }
        if (k0 + 32 < DD) {
            const float* ap = &x[(size_t)(m0 + arow) * DD + k0 + 32 + aseg];
            #pragma unroll
            for (int j = 0; j < 4; j++) pa[j] = *(const float4*)(ap + 4 * j);
            if (tid < 128) {
                const float* bp = &W[(size_t)arow * DD + k0 + 32 + aseg];
                #pragma unroll
                for (int j = 0; j < 4; j++) pb[j] = *(const float4*)(bp + 4 * j);
            }
        }
        __syncthreads();

        bfrag af[2], bf[4];
        #pragma unroll
        for (int mt = 0; mt < 2; mt++)
            af[mt] = *(const bfrag*)&As[wave * 32 + mt * 16 + ln][q8];
        #pragma unroll
        for (int nt = 0; nt < 4; nt++)
            bf[nt] = *(const bfrag*)&Bs[nt * 16 + ln][q8];
        #pragma unroll
        for (int mt = 0; mt < 2; mt++)
            #pragma unroll
            for (int nt = 0; nt < 4; nt++)
                acc[mt][nt] = __builtin_amdgcn_mfma_f32_16x16x32_bf16(
                    af[mt], bf[nt], acc[mt][nt], 0, 0, 0);
    }

    #pragma unroll
    for (int nt = 0; nt < 4; nt++) {
        const int col = nt * 16 + ln;
        const float ba = (mat == 3) ? b_alpha[col] : 0.0f;
        #pragma unroll
        for (int mt = 0; mt < 2; mt++) {
            #pragma unroll
            for (int r = 0; r < 4; r++) {
                const int row = m0 + wave * 32 + mt * 16 + (lane >> 4) * 4 + r;
                float v = acc[mt][nt][r];
                if (mat == 3) v = sigmoidf_(v + ba);
                C[(size_t)row * NN + col] = v;
            }
        }
    }
}

// ---------------------------------------------------------------------------
// Phase 1.5: per-(b,chunk) Gram matrices for the scan.
// Writes, per (b,c), a 64-row x 128-float block, row s interleaved:
//   pos 2t   = G[s][t]  = k_s . k_t
//   pos 2t+1 = KQ[s][t] = k_s . q_t        (f32, full precision)
// grid (NC2, BB) x 256.
// ---------------------------------------------------------------------------
__global__ __launch_bounds__(256) void gram_kernel(
    const float* __restrict__ k_all, const float* __restrict__ q_all,
    float* __restrict__ gkq)
{
    const int c  = blockIdx.x;
    const int b  = blockIdx.y;
    const int t0 = c * C64;
    const int tid = threadIdx.x;

    __shared__ __align__(16) float Ks[64][68];   // +4 pad: bank spread
    __shared__ __align__(16) float Qs[64][68];

    // stage K, Q (64x64 each)
    {
        const int r = tid >> 2, sg = (tid & 3) * 16;
        const float* kp = &k_all[(size_t)(t0 + r) * (BB * NN) + b * NN + sg];
        const float* qp = &q_all[(size_t)(t0 + r) * (BB * NN) + b * NN + sg];
        #pragma unroll
        for (int j = 0; j < 4; ++j) {
            *(float4*)&Ks[r][sg + 4 * j] = *(const float4*)(kp + 4 * j);
            *(float4*)&Qs[r][sg + 4 * j] = *(const float4*)(qp + 4 * j);
        }
    }
    __syncthreads();

    const int ti = tid >> 4, tj = tid & 15;
    float g[4][4] = {}, kq[4][4] = {};
    #pragma unroll
    for (int c4 = 0; c4 < 16; ++c4) {
        float4 ka[4], kb[4], qb[4];
        #pragma unroll
        for (int r = 0; r < 4; ++r) {
            ka[r] = *(const float4*)&Ks[4 * ti + r][c4 * 4];
            kb[r] = *(const float4*)&Ks[4 * tj + r][c4 * 4];
            qb[r] = *(const float4*)&Qs[4 * tj + r][c4 * 4];
        }
        #pragma unroll
        for (int r = 0; r < 4; ++r)
            #pragma unroll
            for (int q = 0; q < 4; ++q) {
                g[r][q]  = fmaf(ka[r].x, kb[q].x, g[r][q]);
                g[r][q]  = fmaf(ka[r].y, kb[q].y, g[r][q]);
                g[r][q]  = fmaf(ka[r].z, kb[q].z, g[r][q]);
                g[r][q]  = fmaf(ka[r].w, kb[q].w, g[r][q]);
                kq[r][q] = fmaf(ka[r].x, qb[q].x, kq[r][q]);
                kq[r][q] = fmaf(ka[r].y, qb[q].y, kq[r][q]);
                kq[r][q] = fmaf(ka[r].z, qb[q].z, kq[r][q]);
                kq[r][q] = fmaf(ka[r].w, qb[q].w, kq[r][q]);
            }
    }

    float* base = gkq + (size_t)(b * NC2 + c) * 64 * 128;
    #pragma unroll
    for (int r = 0; r < 4; ++r) {
        const int s = 4 * ti + r;
        #pragma unroll
        for (int q = 0; q < 4; ++q) {
            const int t = 4 * tj + q;
            float2 gv; gv.x = g[r][q]; gv.y = kq[r][q];
            *(float2*)&base[s * 128 + 2 * t] = gv;
        }
    }
}

// ---------------------------------------------------------------------------
// Phase 2: scan, chunked-scalar form. One wave per (b,row) chain.
// Within a 64-step chunk with P_t = cumprod(alpha), chat_j = c_j/P_j:
//   r_s  = Pm_s*(h_s + A_s),  A_s = sum_{j<s} chat_j*G[j][s]   (readlane)
//   chat = (w_s/P_s)*sigmoid(d*r+b);  A_t += chat*G[s][t];
//   B_t += chat*KQ[s][t];  Sa   += chat*k_s[col];
//   o_t  = P_t*(hq_t + B_t)  (B latched at t==s);  S' = P_63*(S + Sa)
// Serial chain per step: readlane -> fma -> exp2 -> add -> rcp -> mul -> fma.
// K/Q staged to LDS with XOR-16 granule swizzle applied on the GLOBAL source
// address (linear global_load_lds dest). alpha/w gathered per-lane.
// grid (BB, 16) x 256 (4 waves = 4 rows) -> 128 blocks, 1 wave/SIMD.
// ---------------------------------------------------------------------------
__global__ __launch_bounds__(256) void scan_kernel(
    const float* __restrict__ gkq,
    const float* __restrict__ k_all, const float* __restrict__ q_all,
    const float* __restrict__ a_all, const float* __restrict__ v_all,
    const float* __restrict__ S0,
    const float* __restrict__ d_g, const float* __restrict__ b_g,
    float* __restrict__ out, float* __restrict__ S_final)
{
    const int b    = blockIdx.x;
    const int rg   = blockIdx.y;
    const int tid  = threadIdx.x;
    const int lane = tid & 63;
    const int wave = tid >> 6;        // 0..3
    const int row  = rg * 4 + wave;

    __shared__ __align__(16) float gk[2][64 * 128];   // {G,KQ} interleaved, 64 KB
    __shared__ __align__(16) float Kl[2][64 * 64];    // K swizzled, 32 KB
    __shared__ __align__(16) float Ql[2][64 * 64];    // Q swizzled, 32 KB
    __shared__ __align__(16) float unif[4][256];      // per-wave {e1,e0,u,_}/step
    __shared__ __align__(16) float sbuf[4][64];       // per-wave S broadcast

    float S = S0[((size_t)b * NN + row) * NN + lane];
    const float L2E  = 1.4426950408889634f;
    const float ndg2 = -d_g[row] * L2E;
    const float nbg2 = -b_g[row] * L2E;

    const float* gkq_b = gkq + (size_t)b * NC2 * 64 * 128;

    const int s_loc = lane >> 4;      // row within a 4-row K/Q stage call
    const int gr    = lane & 15;      // granule within row

    auto stage = [&](int c, int db) {
        // G/KQ rows: wave w covers rows w*16 .. w*16+15, 2 rows per gll16
        const float* src = gkq_b + (size_t)c * 64 * 128;
        #pragma unroll
        for (int j = 0; j < 8; ++j) {
            const int off = (wave * 16 + 2 * j) * 128;
            gll16(src + off + lane * 4, &gk[db][off]);
        }
        // K/Q: 4 rows per gll16 (16 lanes per row), XOR-swizzled global source
        #pragma unroll
        for (int j = 0; j < 4; ++j) {
            const int r0 = wave * 16 + 4 * j;
            const int s  = r0 + s_loc;
            const int gg = gr ^ (s & 15);
            const size_t goff = ((size_t)(c * C64 + s) * BB + b) * NN + gg * 4;
            gll16(k_all + goff, &Kl[db][r0 * 64]);
            gll16(q_all + goff, &Ql[db][r0 * 64]);
        }
    };

    float a_nx, v_nx;
    auto aw_load = [&](int c) {
        const size_t goff = ((size_t)(c * C64 + lane) * BB + b) * NN + row;
        a_nx = a_all[goff];
        v_nx = v_all[goff];
    };

    stage(0, 0);
    aw_load(0);

    for (int c = 0; c < NC2; ++c) {
        const int db = c & 1;
        const float ac = a_nx;
        const float wc = (1.0f - a_nx) * v_nx;
        __syncthreads();                       // chunk c staged; buf db^1 free
        if (c + 1 < NC2) { aw_load(c + 1); stage(c + 1, db ^ 1); }

        // ---- prefix products over alpha (lane = step) ----
        float P = ac;
        #pragma unroll
        for (int off = 1; off < 64; off <<= 1) {
            float v = __shfl_up(P, off, 64);
            if (lane >= off) P *= v;
        }
        float Pm = __shfl_up(P, 1, 64);
        if (lane == 0) Pm = 1.0f;
        const float u = wc * rcp_(P);

        // ---- h_t = S.k_t, hq_t = S.q_t (lane = t) ----
        sbuf[wave][lane] = S;
        const float* Kb = &Kl[db][0];
        const float* Qb = &Ql[db][0];
        float4 ha = {0.f, 0.f, 0.f, 0.f};
        float4 hb = {0.f, 0.f, 0.f, 0.f};
        #pragma unroll
        for (int g4 = 0; g4 < 16; ++g4) {
            const int idx = lane * 64 + ((g4 ^ (lane & 15)) << 2);
            float4 kv = *(const float4*)&Kb[idx];
            float4 qv = *(const float4*)&Qb[idx];
            float4 sv = *(const float4*)&sbuf[wave][g4 << 2];
            ha.x = fmaf(kv.x, sv.x, ha.x); ha.y = fmaf(kv.y, sv.y, ha.y);
            ha.z = fmaf(kv.z, sv.z, ha.z); ha.w = fmaf(kv.w, sv.w, ha.w);
            hb.x = fmaf(qv.x, sv.x, hb.x); hb.y = fmaf(qv.y, sv.y, hb.y);
            hb.z = fmaf(qv.z, sv.z, hb.z); hb.w = fmaf(qv.w, sv.w, hb.w);
        }
        const float h  = (ha.x + ha.y) + (ha.z + ha.w);
        const float hq = (hb.x + hb.y) + (hb.z + hb.w);
        const float e1 = ndg2 * Pm;                  // sigmoid arg = e1*A_s + e0
        const float e0 = fmaf(e1, h, nbg2);
        {
            float4 uv; uv.x = e1; uv.y = e0; uv.z = u; uv.w = 0.0f;
            *(float4*)&unif[wave][lane * 4] = uv;
        }

        // ---- serial scalar chain over 64 steps ----
        float A = 0.f, Bacc = 0.f, Bl = 0.f, Sa = 0.f;
        const float* gkb = &gk[db][0];
        float2 gk_c = *(const float2*)&gkb[lane * 2];        // row 0
        float  k_c  = Kb[lane];                              // row 0 (s&15 == 0)
        float4 u_c  = *(const float4*)&unif[wave][0];

        for (int s8 = 0; s8 < 64; s8 += 8) {
            #pragma unroll
            for (int k = 0; k < 8; ++k) {
                const int s  = s8 + k;
                const int sn = (s + 1) & 63;
                // distance-1 prefetch (wraps; discarded on last step)
                float2 gk_n = *(const float2*)&gkb[sn * 128 + lane * 2];
                float  k_n  = Kb[sn * 64 + (lane ^ ((sn & 15) << 2))];
                float4 u_n  = *(const float4*)&unif[wave][sn * 4];

                const float Ab = bcastlane(A, s);
                const float ch = u_c.z *
                    rcp_(1.0f + exp2_(fmaf(u_c.x, Ab, u_c.y)));
                A    = fmaf(ch, gk_c.x, A);
                Bacc = fmaf(ch, gk_c.y, Bacc);
                Sa   = fmaf(ch, k_c,    Sa);
                Bl   = (lane == s) ? Bacc : Bl;
                gk_c = gk_n; k_c = k_n; u_c = u_n;
            }
        }

        // ---- epilogue: outputs + state update ----
        const float o = P * (hq + Bl);
        const float y = o * o * rcp_(1.0f + exp2_(-o * L2E));
        out[((size_t)(c * C64 + lane) * BB + b) * NN + row] = y;
        const float Pl = bcastlane(P, 63);
        S = Pl * (S + Sa);
    }

    S_final[((size_t)b * NN + row) * NN + lane] = S;
}

// ---------------------------------------------------------------------------
extern "C" void kernel_launch(void* const* d_in, const int* in_sizes, int n_in,
                              void* d_out, int out_size, void* d_ws, size_t ws_size,
                              hipStream_t stream) {
    const float* x       = (const float*)d_in[0];
    const float* S0      = (const float*)d_in[1];
    const float* W_k     = (const float*)d_in[2];
    const float* W_v     = (const float*)d_in[3];
    const float* W_q     = (const float*)d_in[4];
    const float* W_alpha = (const float*)d_in[5];
    const float* b_alpha = (const float*)d_in[6];
    const float* d_g     = (const float*)d_in[7];
    const float* b_g     = (const float*)d_in[8];
    float* out = (float*)d_out;

    const size_t arr = (size_t)TT * BB * NN;          // 1M floats
    float* ws    = (float*)d_ws;
    float* k_all = ws;
    float* v_all = ws + arr;
    float* q_all = ws + 2 * arr;
    float* a_all = ws + 3 * arr;
    float* gkq   = ws + 4 * arr;   // 8*32*64*128 = 2M floats -> 24 MB total ws

    proj_gemm_kernel<<<dim3(4, TT * BB / 128), 256, 0, stream>>>(
        x, W_k, W_v, W_q, W_alpha, b_alpha, k_all, v_all, q_all, a_all);

    gram_kernel<<<dim3(NC2, BB), 256, 0, stream>>>(k_all, q_all, gkq);

    scan_kernel<<<dim3(BB, 16), 256, 0, stream>>>(
        gkq, k_all, q_all, a_all, v_all, S0, d_g, b_g, out, out + arr);
}

// Round 3
// 306.545 us; speedup vs baseline: 1.5732x; 1.0360x over previous
//
#include <hip/hip_runtime.h>

#define TT 2048
#define BB 8
#define DD 1024
#define NN 64
#define C64 64            // timesteps per chunk (= wavefront size)
#define NC2 (TT / C64)    // 32 chunks

typedef __attribute__((ext_vector_type(8))) short bfrag;    // 8 bf16 (4 VGPRs)
typedef __attribute__((ext_vector_type(4))) float f32x4;    // MFMA C/D
typedef __attribute__((ext_vector_type(8))) unsigned short ushort8;

__device__ __forceinline__ float rcp_(float x) { return __builtin_amdgcn_rcpf(x); }
__device__ __forceinline__ float exp2_(float x) {
#if __has_builtin(__builtin_amdgcn_exp2f)
    return __builtin_amdgcn_exp2f(x);
#else
    return exp2f(x);
#endif
}
// fast sigmoid for proj epilogue
__device__ __forceinline__ float sigmoidf_(float x) {
    return rcp_(1.0f + __expf(-x));
}
__device__ __forceinline__ float bcastlane(float x, int l) {
    return __int_as_float(__builtin_amdgcn_readlane(__float_as_int(x), l));
}

// f32 -> bf16 round-to-nearest-even
__device__ __forceinline__ unsigned short cvt_bf16(float f) {
    unsigned int u = __float_as_uint(f);
    return (unsigned short)((u + 0x7FFF + ((u >> 16) & 1)) >> 16);
}

// async global->LDS, 16 B/lane (LDS dest is wave-uniform base + lane*16)
__device__ __forceinline__ void gll16(const float* g, float* l) {
    __builtin_amdgcn_global_load_lds(
        (const __attribute__((address_space(1))) void*)g,
        (__attribute__((address_space(3))) void*)l, 16, 0, 0);
}

// ---------------------------------------------------------------------------
// Phase 1: projections via bf16 MFMA (unchanged, known good).
// ---------------------------------------------------------------------------
__global__ __launch_bounds__(256) void proj_gemm_kernel(
    const float* __restrict__ x,
    const float* __restrict__ W0, const float* __restrict__ W1,
    const float* __restrict__ W2, const float* __restrict__ W3,
    const float* __restrict__ b_alpha,
    float* __restrict__ O0, float* __restrict__ O1,
    float* __restrict__ O2, float* __restrict__ O3)
{
    const int mat = blockIdx.x;
    const float* __restrict__ W = (mat == 0) ? W0 : (mat == 1) ? W1 : (mat == 2) ? W2 : W3;
    float* __restrict__ C       = (mat == 0) ? O0 : (mat == 1) ? O1 : (mat == 2) ? O2 : O3;

    const int m0   = blockIdx.y * 128;
    const int tid  = threadIdx.x;
    const int lane = tid & 63;
    const int wave = tid >> 6;
    const int ln   = lane & 15;
    const int q8   = (lane >> 4) * 8;

    __shared__ unsigned short As[128][40];
    __shared__ unsigned short Bs[64][40];

    f32x4 acc[2][4] = {};

    const int arow = tid >> 1;
    const int aseg = (tid & 1) * 16;

    float4 pa[4], pb[4];
    {
        const float* ap = &x[(size_t)(m0 + arow) * DD + aseg];
        #pragma unroll
        for (int j = 0; j < 4; j++) pa[j] = *(const float4*)(ap + 4 * j);
        if (tid < 128) {
            const float* bp = &W[(size_t)arow * DD + aseg];
            #pragma unroll
            for (int j = 0; j < 4; j++) pb[j] = *(const float4*)(bp + 4 * j);
        }
    }

    for (int k0 = 0; k0 < DD; k0 += 32) {
        __syncthreads();
        {
            unsigned short t16[16];
            const float* pf = (const float*)pa;
            #pragma unroll
            for (int j = 0; j < 16; j++) t16[j] = cvt_bf16(pf[j]);
            *(ushort8*)&As[arow][aseg]     = *(ushort8*)&t16[0];
            *(ushort8*)&As[arow][aseg + 8] = *(ushort8*)&t16[8];
            if (tid < 128) {
                const float* qf = (const float*)pb;
                #pragma unroll
                for (int j = 0; j < 16; j++) t16[j] = cvt_bf16(qf[j]);
                *(ushort8*)&Bs[arow][aseg]     = *(ushort8*)&t16[0];
                *(ushort8*)&Bs[arow][aseg + 8] = *(ushort8*)&t16[8];
            }
        }
        if (k0 + 32 < DD) {
            const float* ap = &x[(size_t)(m0 + arow) * DD + k0 + 32 + aseg];
            #pragma unroll
            for (int j = 0; j < 4; j++) pa[j] = *(const float4*)(ap + 4 * j);
            if (tid < 128) {
                const float* bp = &W[(size_t)arow * DD + k0 + 32 + aseg];
                #pragma unroll
                for (int j = 0; j < 4; j++) pb[j] = *(const float4*)(bp + 4 * j);
            }
        }
        __syncthreads();

        bfrag af[2], bf[4];
        #pragma unroll
        for (int mt = 0; mt < 2; mt++)
            af[mt] = *(const bfrag*)&As[wave * 32 + mt * 16 + ln][q8];
        #pragma unroll
        for (int nt = 0; nt < 4; nt++)
            bf[nt] = *(const bfrag*)&Bs[nt * 16 + ln][q8];
        #pragma unroll
        for (int mt = 0; mt < 2; mt++)
            #pragma unroll
            for (int nt = 0; nt < 4; nt++)
                acc[mt][nt] = __builtin_amdgcn_mfma_f32_16x16x32_bf16(
                    af[mt], bf[nt], acc[mt][nt], 0, 0, 0);
    }

    #pragma unroll
    for (int nt = 0; nt < 4; nt++) {
        const int col = nt * 16 + ln;
        const float ba = (mat == 3) ? b_alpha[col] : 0.0f;
        #pragma unroll
        for (int mt = 0; mt < 2; mt++) {
            #pragma unroll
            for (int r = 0; r < 4; r++) {
                const int row = m0 + wave * 32 + mt * 16 + (lane >> 4) * 4 + r;
                float v = acc[mt][nt][r];
                if (mat == 3) v = sigmoidf_(v + ba);
                C[(size_t)row * NN + col] = v;
            }
        }
    }
}

// ---------------------------------------------------------------------------
// Phase 1.5: per-(b,chunk) Gram matrices for the scan (unchanged).
//   pos 2t   = G[s][t]  = k_s . k_t
//   pos 2t+1 = KQ[s][t] = k_s . q_t        (f32, full precision)
// grid (NC2, BB) x 256.
// ---------------------------------------------------------------------------
__global__ __launch_bounds__(256) void gram_kernel(
    const float* __restrict__ k_all, const float* __restrict__ q_all,
    float* __restrict__ gkq)
{
    const int c  = blockIdx.x;
    const int b  = blockIdx.y;
    const int t0 = c * C64;
    const int tid = threadIdx.x;

    __shared__ __align__(16) float Ks[64][68];   // +4 pad: bank spread
    __shared__ __align__(16) float Qs[64][68];

    // stage K, Q (64x64 each)
    {
        const int r = tid >> 2, sg = (tid & 3) * 16;
        const float* kp = &k_all[(size_t)(t0 + r) * (BB * NN) + b * NN + sg];
        const float* qp = &q_all[(size_t)(t0 + r) * (BB * NN) + b * NN + sg];
        #pragma unroll
        for (int j = 0; j < 4; ++j) {
            *(float4*)&Ks[r][sg + 4 * j] = *(const float4*)(kp + 4 * j);
            *(float4*)&Qs[r][sg + 4 * j] = *(const float4*)(qp + 4 * j);
        }
    }
    __syncthreads();

    const int ti = tid >> 4, tj = tid & 15;
    float g[4][4] = {}, kq[4][4] = {};
    #pragma unroll
    for (int c4 = 0; c4 < 16; ++c4) {
        float4 ka[4], kb[4], qb[4];
        #pragma unroll
        for (int r = 0; r < 4; ++r) {
            ka[r] = *(const float4*)&Ks[4 * ti + r][c4 * 4];
            kb[r] = *(const float4*)&Ks[4 * tj + r][c4 * 4];
            qb[r] = *(const float4*)&Qs[4 * tj + r][c4 * 4];
        }
        #pragma unroll
        for (int r = 0; r < 4; ++r)
            #pragma unroll
            for (int q = 0; q < 4; ++q) {
                g[r][q]  = fmaf(ka[r].x, kb[q].x, g[r][q]);
                g[r][q]  = fmaf(ka[r].y, kb[q].y, g[r][q]);
                g[r][q]  = fmaf(ka[r].z, kb[q].z, g[r][q]);
                g[r][q]  = fmaf(ka[r].w, kb[q].w, g[r][q]);
                kq[r][q] = fmaf(ka[r].x, qb[q].x, kq[r][q]);
                kq[r][q] = fmaf(ka[r].y, qb[q].y, kq[r][q]);
                kq[r][q] = fmaf(ka[r].z, qb[q].z, kq[r][q]);
                kq[r][q] = fmaf(ka[r].w, qb[q].w, kq[r][q]);
            }
    }

    float* base = gkq + (size_t)(b * NC2 + c) * 64 * 128;
    #pragma unroll
    for (int r = 0; r < 4; ++r) {
        const int s = 4 * ti + r;
        #pragma unroll
        for (int q = 0; q < 4; ++q) {
            const int t = 4 * tj + q;
            float2 gv; gv.x = g[r][q]; gv.y = kq[r][q];
            *(float2*)&base[s * 128 + 2 * t] = gv;
        }
    }
}

// ---------------------------------------------------------------------------
// Phase 2: scan, chunked-scalar form. One wave per (b,row) chain.
// Serial chain per step: readlane(A) -> fma -> exp2 -> add -> rcp -> fma.
// All other per-step inputs come from registers:
//   e1/e0/u per-step scalars via v_readlane (no LDS),
//   G/KQ row + K row via a depth-4 register ring prefetched from LDS
//   (~4 steps = ~200 cycles of cover for ~120-cycle LDS latency).
// grid (BB, 16) x 256 (4 waves = 4 rows) -> 128 blocks, 1 wave/SIMD.
// ---------------------------------------------------------------------------
__global__ __launch_bounds__(256) void scan_kernel(
    const float* __restrict__ gkq,
    const float* __restrict__ k_all, const float* __restrict__ q_all,
    const float* __restrict__ a_all, const float* __restrict__ v_all,
    const float* __restrict__ S0,
    const float* __restrict__ d_g, const float* __restrict__ b_g,
    float* __restrict__ out, float* __restrict__ S_final)
{
    const int b    = blockIdx.x;
    const int rg   = blockIdx.y;
    const int tid  = threadIdx.x;
    const int lane = tid & 63;
    const int wave = tid >> 6;        // 0..3
    const int row  = rg * 4 + wave;

    __shared__ __align__(16) float gk[2][64 * 128];   // {G,KQ} interleaved, 64 KB
    __shared__ __align__(16) float Kl[2][64 * 64];    // K swizzled, 32 KB
    __shared__ __align__(16) float Ql[2][64 * 64];    // Q swizzled, 32 KB
    __shared__ __align__(16) float sbuf[4][64];       // per-wave S broadcast

    float S = S0[((size_t)b * NN + row) * NN + lane];
    const float L2E  = 1.4426950408889634f;
    const float ndg2 = -d_g[row] * L2E;
    const float nbg2 = -b_g[row] * L2E;

    const float* gkq_b = gkq + (size_t)b * NC2 * 64 * 128;

    const int s_loc = lane >> 4;      // row within a 4-row K/Q stage call
    const int gr    = lane & 15;      // granule within row

    auto stage = [&](int c, int db) {
        // G/KQ rows: wave w covers rows w*16 .. w*16+15, 2 rows per gll16
        const float* src = gkq_b + (size_t)c * 64 * 128;
        #pragma unroll
        for (int j = 0; j < 8; ++j) {
            const int off = (wave * 16 + 2 * j) * 128;
            gll16(src + off + lane * 4, &gk[db][off]);
        }
        // K/Q: 4 rows per gll16 (16 lanes per row), XOR-swizzled global source
        #pragma unroll
        for (int j = 0; j < 4; ++j) {
            const int r0 = wave * 16 + 4 * j;
            const int s  = r0 + s_loc;
            const int gg = gr ^ (s & 15);
            const size_t goff = ((size_t)(c * C64 + s) * BB + b) * NN + gg * 4;
            gll16(k_all + goff, &Kl[db][r0 * 64]);
            gll16(q_all + goff, &Ql[db][r0 * 64]);
        }
    };

    float a_nx, v_nx;
    auto aw_load = [&](int c) {
        const size_t goff = ((size_t)(c * C64 + lane) * BB + b) * NN + row;
        a_nx = a_all[goff];
        v_nx = v_all[goff];
    };

    stage(0, 0);
    aw_load(0);

    for (int c = 0; c < NC2; ++c) {
        const int db = c & 1;
        const float ac = a_nx;
        const float wc = (1.0f - a_nx) * v_nx;
        __syncthreads();                       // chunk c staged; buf db^1 free
        if (c + 1 < NC2) { aw_load(c + 1); stage(c + 1, db ^ 1); }

        // ---- prefix products over alpha (lane = step) ----
        float P = ac;
        #pragma unroll
        for (int off = 1; off < 64; off <<= 1) {
            float v = __shfl_up(P, off, 64);
            if (lane >= off) P *= v;
        }
        float Pm = __shfl_up(P, 1, 64);
        if (lane == 0) Pm = 1.0f;

        // ---- h_t = S.k_t, hq_t = S.q_t (lane = t) ----
        sbuf[wave][lane] = S;
        const float* Kb  = &Kl[db][0];
        const float* Qb  = &Ql[db][0];
        const float* gkb = &gk[db][0];
        float4 ha = {0.f, 0.f, 0.f, 0.f};
        float4 hb = {0.f, 0.f, 0.f, 0.f};
        #pragma unroll
        for (int g4 = 0; g4 < 16; ++g4) {
            const int idx = lane * 64 + ((g4 ^ gr) << 2);
            float4 kv = *(const float4*)&Kb[idx];
            float4 qv = *(const float4*)&Qb[idx];
            float4 sv = *(const float4*)&sbuf[wave][g4 << 2];
            ha.x = fmaf(kv.x, sv.x, ha.x); ha.y = fmaf(kv.y, sv.y, ha.y);
            ha.z = fmaf(kv.z, sv.z, ha.z); ha.w = fmaf(kv.w, sv.w, ha.w);
            hb.x = fmaf(qv.x, sv.x, hb.x); hb.y = fmaf(qv.y, sv.y, hb.y);
            hb.z = fmaf(qv.z, sv.z, hb.z); hb.w = fmaf(qv.w, sv.w, hb.w);
        }
        const float h  = (ha.x + ha.y) + (ha.z + ha.w);
        const float hq = (hb.x + hb.y) + (hb.z + hb.w);

        // per-step scalars, kept in registers (lane = step)
        const float u  = wc * rcp_(P);
        const float e1 = ndg2 * Pm;                  // sigmoid arg = e1*A_s + e0
        const float e0 = fmaf(e1, h, nbg2);

        // ---- depth-4 register ring prefetch of rows 0..3 ----
        float2 gkr[4];
        float  kr[4];
        #pragma unroll
        for (int j = 0; j < 4; ++j) {
            gkr[j] = *(const float2*)&gkb[j * 128 + lane * 2];
            kr[j]  = Kb[j * 64 + (lane ^ (j << 2))];
        }

        // ---- serial scalar chain over 64 steps (fully unrolled) ----
        float A = 0.f, Bacc = 0.f, Bl = 0.f, Sa = 0.f;
        #pragma unroll
        for (int s = 0; s < 64; ++s) {
            const int slot = s & 3;
            const float2 g_c = gkr[slot];
            const float  k_c = kr[slot];
            // off-chain scalar broadcasts + row pre-scale by u_s
            const float us  = bcastlane(u, s);
            const float e1s = bcastlane(e1, s);
            const float e0s = bcastlane(e0, s);
            const float gA = us * g_c.x;
            const float gB = us * g_c.y;
            const float gS = us * k_c;
            // chain: readlane -> fma -> exp2 -> add -> rcp -> fma
            const float Ab  = bcastlane(A, s);
            const float sig = rcp_(1.0f + exp2_(fmaf(e1s, Ab, e0s)));
            A    = fmaf(sig, gA, A);
            Bacc = fmaf(sig, gB, Bacc);
            Sa   = fmaf(sig, gS, Sa);
            Bl   = (lane == s) ? Bacc : Bl;
            // refill slot with row s+4 (wraps; discarded values harmless)
            const int sn = (s + 4) & 63;
            gkr[slot] = *(const float2*)&gkb[sn * 128 + lane * 2];
            kr[slot]  = Kb[sn * 64 + (lane ^ ((sn & 15) << 2))];
        }

        // ---- epilogue: outputs + state update ----
        const float o = P * (hq + Bl);
        const float y = o * o * rcp_(1.0f + exp2_(-o * L2E));
        out[((size_t)(c * C64 + lane) * BB + b) * NN + row] = y;
        const float Pl = bcastlane(P, 63);
        S = Pl * (S + Sa);
    }

    S_final[((size_t)b * NN + row) * NN + lane] = S;
}

// ---------------------------------------------------------------------------
extern "C" void kernel_launch(void* const* d_in, const int* in_sizes, int n_in,
                              void* d_out, int out_size, void* d_ws, size_t ws_size,
                              hipStream_t stream) {
    const float* x       = (const float*)d_in[0];
    const float* S0      = (const float*)d_in[1];
    const float* W_k     = (const float*)d_in[2];
    const float* W_v     = (const float*)d_in[3];
    const float* W_q     = (const float*)d_in[4];
    const float* W_alpha = (const float*)d_in[5];
    const float* b_alpha = (const float*)d_in[6];
    const float* d_g     = (const float*)d_in[7];
    const float* b_g     = (const float*)d_in[8];
    float* out = (float*)d_out;

    const size_t arr = (size_t)TT * BB * NN;          // 1M floats
    float* ws    = (float*)d_ws;
    float* k_all = ws;
    float* v_all = ws + arr;
    float* q_all = ws + 2 * arr;
    float* a_all = ws + 3 * arr;
    float* gkq   = ws + 4 * arr;   // 8*32*64*128 = 2M floats -> 24 MB total ws

    proj_gemm_kernel<<<dim3(4, TT * BB / 128), 256, 0, stream>>>(
        x, W_k, W_v, W_q, W_alpha, b_alpha, k_all, v_all, q_all, a_all);

    gram_kernel<<<dim3(NC2, BB), 256, 0, stream>>>(k_all, q_all, gkq);

    scan_kernel<<<dim3(BB, 16), 256, 0, stream>>>(
        gkq, k_all, q_all, a_all, v_all, S0, d_g, b_g, out, out + arr);
}